// Round 1
// baseline (2747.375 us; speedup 1.0000x reference)
//
#include <hip/hip_runtime.h>

#define EPS_BN 1e-5f

constexpr int N_IN_C  = 100000;
constexpr int N_OUT_C = 400000;
constexpr int KTAPS   = 27;
constexpr int M_UP_C  = 100000;
constexpr int M_C_C   = 120000;

// ---------------------------------------------------------------------------
// Sparse conv scatter, C_in = 64 (split as two 32-channel sources a/b),
// C_out = 32.  blockIdx.y = kernel tap k.  Wave64 = (c in [0,32), h in {0,1});
// each half-wave owns one (k,m) pair; each lane computes the full 64-wide dot
// for its output channel, then one atomicAdd.
// Weights for tap k live in 64 VGPRs per lane (w[k][j][c], j=0..63).
// ---------------------------------------------------------------------------
__global__ __launch_bounds__(256) void conv64_scatter(
    const float* __restrict__ xa, int lda,
    const float* __restrict__ xb, int ldb,
    const float* __restrict__ w,        // [K,64,32]
    const int*   __restrict__ in_idx,   // [K,M]
    const int*   __restrict__ out_idx,  // [K,M]
    float*       __restrict__ acc,      // [N_OUT,32]
    int M)
{
    const int k    = blockIdx.y;
    const int lane = threadIdx.x & 63;
    const int wid  = threadIdx.x >> 6;   // wave in block, 0..3
    const int c    = lane & 31;
    const int h    = lane >> 5;          // pair slot within wave

    float wreg[64];
    const float* wk = w + (size_t)k * 64 * 32 + c;
#pragma unroll
    for (int j = 0; j < 64; ++j) wreg[j] = wk[j * 32];

    const int* in_k  = in_idx  + (size_t)k * M;
    const int* out_k = out_idx + (size_t)k * M;

    for (int pb = (blockIdx.x * 4 + wid) * 2; pb < M; pb += gridDim.x * 8) {
        const int  p     = pb + h;
        const bool valid = (p < M);
        const int  pi    = valid ? p : (M - 1);
        const int  in    = in_k[pi];
        const int  out   = out_k[pi];
        const float* ra  = xa + (size_t)in * lda;
        const float* rb  = xb + (size_t)in * ldb;
        float a = 0.f;
#pragma unroll
        for (int q = 0; q < 8; ++q) {
            const float4 v = *reinterpret_cast<const float4*>(ra + q * 4);
            a = fmaf(v.x, wreg[q * 4 + 0], a);
            a = fmaf(v.y, wreg[q * 4 + 1], a);
            a = fmaf(v.z, wreg[q * 4 + 2], a);
            a = fmaf(v.w, wreg[q * 4 + 3], a);
        }
#pragma unroll
        for (int q = 0; q < 8; ++q) {
            const float4 v = *reinterpret_cast<const float4*>(rb + q * 4);
            a = fmaf(v.x, wreg[32 + q * 4 + 0], a);
            a = fmaf(v.y, wreg[32 + q * 4 + 1], a);
            a = fmaf(v.z, wreg[32 + q * 4 + 2], a);
            a = fmaf(v.w, wreg[32 + q * 4 + 3], a);
        }
        if (valid) atomicAdd(&acc[(size_t)out * 32 + c], a);
    }
}

// Same, C_in = 32 (single source).
__global__ __launch_bounds__(256) void conv32_scatter(
    const float* __restrict__ x,        // [*,32]
    const float* __restrict__ w,        // [K,32,32]
    const int*   __restrict__ in_idx,
    const int*   __restrict__ out_idx,
    float*       __restrict__ acc,
    int M)
{
    const int k    = blockIdx.y;
    const int lane = threadIdx.x & 63;
    const int wid  = threadIdx.x >> 6;
    const int c    = lane & 31;
    const int h    = lane >> 5;

    float wreg[32];
    const float* wk = w + (size_t)k * 32 * 32 + c;
#pragma unroll
    for (int j = 0; j < 32; ++j) wreg[j] = wk[j * 32];

    const int* in_k  = in_idx  + (size_t)k * M;
    const int* out_k = out_idx + (size_t)k * M;

    for (int pb = (blockIdx.x * 4 + wid) * 2; pb < M; pb += gridDim.x * 8) {
        const int  p     = pb + h;
        const bool valid = (p < M);
        const int  pi    = valid ? p : (M - 1);
        const int  in    = in_k[pi];
        const int  out   = out_k[pi];
        const float* r   = x + (size_t)in * 32;
        float a = 0.f;
#pragma unroll
        for (int q = 0; q < 8; ++q) {
            const float4 v = *reinterpret_cast<const float4*>(r + q * 4);
            a = fmaf(v.x, wreg[q * 4 + 0], a);
            a = fmaf(v.y, wreg[q * 4 + 1], a);
            a = fmaf(v.z, wreg[q * 4 + 2], a);
            a = fmaf(v.w, wreg[q * 4 + 3], a);
        }
        if (valid) atomicAdd(&acc[(size_t)out * 32 + c], a);
    }
}

// ---------------------------------------------------------------------------
// BN statistics: per-channel sum and sum-of-squares over N rows (C=32).
// stats[c] = sum, stats[32+c] = sumsq  (must be zeroed before launch).
// ---------------------------------------------------------------------------
__global__ __launch_bounds__(256) void bn_stats_kernel(
    const float* __restrict__ x, float* __restrict__ stats, int n)
{
    const int c = threadIdx.x & 31;
    const int s = threadIdx.x >> 5;   // 0..7 row streams per block
    float sum = 0.f, sq = 0.f;
    for (long r = (long)blockIdx.x * 8 + s; r < n; r += (long)gridDim.x * 8) {
        const float v = x[r * 32 + c];
        sum += v;
        sq  = fmaf(v, v, sq);
    }
    __shared__ float ls[8][33];
    __shared__ float lq[8][33];
    ls[s][c] = sum;
    lq[s][c] = sq;
    __syncthreads();
    if (threadIdx.x < 32) {
        float ts = 0.f, tq = 0.f;
#pragma unroll
        for (int i = 0; i < 8; ++i) { ts += ls[i][c]; tq += lq[i][c]; }
        atomicAdd(&stats[c], ts);
        atomicAdd(&stats[32 + c], tq);
    }
}

// ---------------------------------------------------------------------------
// y = relu((x - mean) * rsqrt(var + eps) * g + bt)
// ---------------------------------------------------------------------------
__global__ __launch_bounds__(256) void bn_relu_kernel(
    const float* __restrict__ h,
    const float* __restrict__ stats,
    const float* __restrict__ g,
    const float* __restrict__ bt,
    float* __restrict__ dst, int n)
{
    const int t = blockIdx.x * 256 + threadIdx.x;
    if (t >= n * 32) return;
    const int c = t & 31;
    const float invn = 1.f / (float)n;
    const float m    = stats[c] * invn;
    const float var  = fmaxf(stats[32 + c] * invn - m * m, 0.f);
    const float inv  = rsqrtf(var + EPS_BN);
    float v = (h[t] - m) * inv * g[c] + bt[c];
    dst[t] = v > 0.f ? v : 0.f;
}

// ---------------------------------------------------------------------------
extern "C" void kernel_launch(void* const* d_in, const int* in_sizes, int n_in,
                              void* d_out, int out_size, void* d_ws, size_t ws_size,
                              hipStream_t stream)
{
    const float* x      = (const float*)d_in[0];
    const float* x_skip = (const float*)d_in[1];
    const float* w_up   = (const float*)d_in[2];
    // d_in[3] = b_up: cancels exactly through train-mode BN -> unused.
    const float* g_up   = (const float*)d_in[4];
    const float* bt_up  = (const float*)d_in[5];
    const float* w1     = (const float*)d_in[6];
    const float* g1     = (const float*)d_in[7];
    const float* bt1    = (const float*)d_in[8];
    const float* w2     = (const float*)d_in[9];
    const float* g2     = (const float*)d_in[10];
    const float* bt2    = (const float*)d_in[11];
    const int* up_in    = (const int*)d_in[12];
    const int* up_out   = (const int*)d_in[13];
    const int* c1_in    = (const int*)d_in[14];
    const int* c1_out   = (const int*)d_in[15];
    const int* c2_in    = (const int*)d_in[16];
    const int* c2_out   = (const int*)d_in[17];

    float* ws    = (float*)d_ws;
    float* hbuf  = ws;                                   // [N_OUT*32] normalized h (h1n, then h2n)
    float* acc   = ws + (size_t)N_OUT_C * 32;            // [N_OUT*32] scatter accumulator
    float* stats = acc + (size_t)N_OUT_C * 32;           // 3 x 64 floats

    const size_t accBytes = (size_t)N_OUT_C * 32 * sizeof(float);
    float* out = (float*)d_out;

    const dim3 blk(256);
    const int elem_blocks = (N_OUT_C * 32 + 255) / 256;
    // grid.x so each wave iterates ~16 pair-steps (8 pairs/block/iter)
    const int gx_up = (M_UP_C + 127) / 128;
    const int gx_c  = (M_C_C + 127) / 128;

    // zero accumulator + all three stats sets
    hipMemsetAsync(acc, 0, accBytes, stream);
    hipMemsetAsync(stats, 0, 192 * sizeof(float), stream);

    // ---- up conv: x[100000,64] @ w_up -> scatter to acc[400000,32] ----
    conv64_scatter<<<dim3(gx_up, KTAPS), blk, 0, stream>>>(
        x, 64, x + 32, 64, w_up, up_in, up_out, acc, M_UP_C);
    bn_stats_kernel<<<2048, blk, 0, stream>>>(acc, stats, N_OUT_C);
    bn_relu_kernel<<<elem_blocks, blk, 0, stream>>>(acc, stats, g_up, bt_up, hbuf, N_OUT_C);

    // ---- conv1: concat([h1n, x_skip]) @ w1 -> acc ----
    hipMemsetAsync(acc, 0, accBytes, stream);
    conv64_scatter<<<dim3(gx_c, KTAPS), blk, 0, stream>>>(
        hbuf, 32, x_skip, 32, w1, c1_in, c1_out, acc, M_C_C);
    bn_stats_kernel<<<2048, blk, 0, stream>>>(acc, stats + 64, N_OUT_C);
    bn_relu_kernel<<<elem_blocks, blk, 0, stream>>>(acc, stats + 64, g1, bt1, hbuf, N_OUT_C);

    // ---- conv2: h2n @ w2 -> acc ----
    hipMemsetAsync(acc, 0, accBytes, stream);
    conv32_scatter<<<dim3(gx_c, KTAPS), blk, 0, stream>>>(
        hbuf, w2, c2_in, c2_out, acc, M_C_C);
    bn_stats_kernel<<<2048, blk, 0, stream>>>(acc, stats + 128, N_OUT_C);
    bn_relu_kernel<<<elem_blocks, blk, 0, stream>>>(acc, stats + 128, g2, bt2, out, N_OUT_C);
}